// Round 14
// baseline (643.360 us; speedup 1.0000x reference)
//
#include <hip/hip_runtime.h>

typedef float f4 __attribute__((ext_vector_type(4)));
typedef _Float16 f16;
typedef f16 f16x8 __attribute__((ext_vector_type(8)));
typedef unsigned short u16;
typedef u16 u16x4 __attribute__((ext_vector_type(4)));
typedef u16 u16x8 __attribute__((ext_vector_type(8)));

#define NE 800000
#define NN 50000

static __device__ __forceinline__ f4 MF(u16x8 a, u16x8 b, f4 c) {
  return __builtin_amdgcn_mfma_f32_16x16x32_f16(
      __builtin_bit_cast(f16x8, a), __builtin_bit_cast(f16x8, b), c, 0, 0, 0);
}
static __device__ __forceinline__ u16 f2h(float x) {
  return __builtin_bit_cast(u16, (f16)x);
}

// ---------------- prologue kernels (proven) ----------------
__global__ void cvt_kernel(const float* __restrict__ na, u16* __restrict__ nh,
                           int n4) {
  int i = blockIdx.x * blockDim.x + threadIdx.x;
  if (i < n4) {
    const f4 v = ((const f4*)na)[i];
    u16x4 h;
#pragma unroll
    for (int j = 0; j < 4; j++) h[j] = f2h(v[j]);
    ((u16x4*)nh)[i] = h;
  }
}

__global__ void zero_int_kernel(int* __restrict__ p, int n) {
  int i = blockIdx.x * blockDim.x + threadIdx.x;
  if (i < n) p[i] = 0;
}

__global__ void hist_kernel(const int* __restrict__ eidx, int* __restrict__ deg) {
  int e = blockIdx.x * blockDim.x + threadIdx.x;
  if (e < NE) atomicAdd(&deg[eidx[NE + e]], 1);
}

__global__ __launch_bounds__(1024)
void scan_kernel(const int* __restrict__ deg, int* __restrict__ offsets,
                 int* __restrict__ cur) {
  __shared__ int buf[2][1024];
  const int t = threadIdx.x;
  const int CH = (NN + 1023) / 1024;  // 49
  const int s = t * CH;
  const int e = (s + CH < NN) ? s + CH : NN;
  int sum = 0;
  for (int i = s; i < e; i++) sum += deg[i];
  buf[0][t] = sum;
  __syncthreads();
  int src = 0;
  for (int d = 1; d < 1024; d <<= 1) {
    int v = buf[src][t];
    if (t >= d) v += buf[src][t - d];
    buf[src ^ 1][t] = v;
    src ^= 1;
    __syncthreads();
  }
  int run = buf[src][t] - sum;  // exclusive prefix
  for (int i = s; i < e; i++) {
    offsets[i] = run;
    cur[i] = run;
    run += deg[i];
  }
  if (e == NN) offsets[NN] = run;
}

__global__ void scatter_kernel(const int* __restrict__ eidx, int* __restrict__ cur,
                               int* __restrict__ elist) {
  int e = blockIdx.x * blockDim.x + threadIdx.x;
  if (e < NE) {
    int slot = atomicAdd(&cur[eidx[NE + e]], 1);
    elist[slot] = e;
  }
}

// ---- edge kernel LDS (u16 units): 64-row tiles, ob overlays x ----
// x: 64 x 192, stride 200 -> [0, 12800)
// h: 64 x 128, stride 136 -> [12800, 21504)
// ob: f32 64x64 aliases sm[0..8192) u16  (x dead after B2)
// total 21504 u16 = 43008 B -> 3 blocks/CU
#define E_XS 200
#define E_HS 136
#define E_HO 12800

__global__ __launch_bounds__(512, 6)
void edge_mlp_kernel(const float* __restrict__ edge_attr,
                     const u16* __restrict__ nh,
                     const int* __restrict__ eidx,
                     const float* __restrict__ W1, const float* __restrict__ b1,
                     const float* __restrict__ W2, const float* __restrict__ b2,
                     const float* __restrict__ gamma, const float* __restrict__ beta,
                     float* __restrict__ edge_out, int ntiles) {
  __shared__ __align__(16) u16 sm[21504];
  const int t = threadIdx.x;
  const int wid = t >> 6, lane = t & 63, g = lane >> 4, l15 = lane & 15;
  const int wr1 = wid >> 2, wc1 = wid & 3;  // L1: 32 rows x 32 cols per wave
  const int wr2 = wid & 1, wc2 = wid >> 1;  // L2: 32 rows x 16 cols per wave

  u16x8 b1f[6][2], b2f[4];
#pragma unroll
  for (int s = 0; s < 6; s++)
#pragma unroll
    for (int ci = 0; ci < 2; ci++) {
      const int col = wc1 * 32 + ci * 16 + l15;
      u16x8 th;
#pragma unroll
      for (int i = 0; i < 8; i++) th[i] = f2h(W1[(s * 32 + g * 8 + i) * 128 + col]);
      b1f[s][ci] = th;
    }
#pragma unroll
  for (int s = 0; s < 4; s++) {
    const int col = wc2 * 16 + l15;
    u16x8 th;
#pragma unroll
    for (int i = 0; i < 8; i++) th[i] = f2h(W2[(s * 32 + g * 8 + i) * 64 + col]);
    b2f[s] = th;
  }
  const float bias1_0 = b1[wc1 * 32 + l15];
  const float bias1_1 = b1[wc1 * 32 + 16 + l15];
  const float bias2 = b2[wc2 * 16 + l15];

  const int r = t >> 3;
  const int c8 = (t & 7) * 8;

  int idxr, idxs;
  u16x8 grecv, gsend;
  f4 ge0, ge1;

#define IDX(TB)                                                \
  {                                                            \
    const long e_ = (long)(TB)*64 + r;                         \
    idxr = eidx[NE + e_];                                      \
    idxs = eidx[e_];                                           \
  }
#define ROWS(TB)                                               \
  {                                                            \
    grecv = *(const u16x8*)&nh[(size_t)idxr * 64 + c8];        \
    gsend = *(const u16x8*)&nh[(size_t)idxs * 64 + c8];        \
    const float* ep_ =                                         \
        &edge_attr[((size_t)(TB)*64 + r) * 64 + c8];           \
    ge0 = __builtin_nontemporal_load((const f4*)ep_);          \
    ge1 = __builtin_nontemporal_load((const f4*)(ep_ + 4));    \
  }

  const int G = gridDim.x;
  const int last = ntiles - 1;
  IDX(blockIdx.x);
  ROWS(blockIdx.x);
  {
    int tn = blockIdx.x + G;
    if (tn > last) tn = last;
    IDX(tn);
  }

  for (int tile = blockIdx.x; tile < ntiles; tile += G) {
    __syncthreads();  // B0: prior LN ob-reads done (ob aliases x region)

    // ---- write prefetched x tile -> LDS ----
    *(u16x8*)&sm[r * E_XS + c8] = grecv;
    *(u16x8*)&sm[r * E_XS + 64 + c8] = gsend;
    {
      u16x8 he;
#pragma unroll
      for (int j = 0; j < 4; j++) {
        he[j] = f2h(ge0[j]);
        he[4 + j] = f2h(ge1[j]);
      }
      *(u16x8*)&sm[r * E_XS + 128 + c8] = he;
    }
    __syncthreads();  // B1: x visible

    // ---- issue next tile's rows + indices two ahead ----
    {
      int tn = tile + G;
      if (tn > last) tn = last;
      ROWS(tn);
      int tn2 = tile + 2 * G;
      if (tn2 > last) tn2 = last;
      IDX(tn2);
    }

    // ---- layer 1: per-wave 32x32 tile of h = relu(x @ W1 + b1) ----
    f4 acc00 = {0.f, 0.f, 0.f, 0.f}, acc01 = {0.f, 0.f, 0.f, 0.f};
    f4 acc10 = {0.f, 0.f, 0.f, 0.f}, acc11 = {0.f, 0.f, 0.f, 0.f};
#pragma unroll
    for (int s = 0; s < 6; s++) {
      const int k = s * 32 + g * 8;
      const u16x8 a0 = *(const u16x8*)&sm[(wr1 * 32 + l15) * E_XS + k];
      const u16x8 a1 = *(const u16x8*)&sm[(wr1 * 32 + 16 + l15) * E_XS + k];
      acc00 = MF(a0, b1f[s][0], acc00);
      acc01 = MF(a0, b1f[s][1], acc01);
      acc10 = MF(a1, b1f[s][0], acc10);
      acc11 = MF(a1, b1f[s][1], acc11);
    }
#pragma unroll
    for (int reg = 0; reg < 4; reg++) {
      const int row0 = wr1 * 32 + 4 * g + reg;
      const int row1 = row0 + 16;
      sm[E_HO + row0 * E_HS + wc1 * 32 + l15] = f2h(fmaxf(acc00[reg] + bias1_0, 0.f));
      sm[E_HO + row0 * E_HS + wc1 * 32 + 16 + l15] = f2h(fmaxf(acc01[reg] + bias1_1, 0.f));
      sm[E_HO + row1 * E_HS + wc1 * 32 + l15] = f2h(fmaxf(acc10[reg] + bias1_0, 0.f));
      sm[E_HO + row1 * E_HS + wc1 * 32 + 16 + l15] = f2h(fmaxf(acc11[reg] + bias1_1, 0.f));
    }
    __syncthreads();  // B2: h visible; ALL x-reads complete (ob may now overlay x)

    // ---- layer 2: per-wave 32x16 tile of o = relu(h @ W2 + b2) ----
    f4 a20 = {0.f, 0.f, 0.f, 0.f}, a21 = {0.f, 0.f, 0.f, 0.f};
#pragma unroll
    for (int s = 0; s < 4; s++) {
      const int k = s * 32 + g * 8;
      const u16x8 h0 = *(const u16x8*)&sm[E_HO + (wr2 * 32 + l15) * E_HS + k];
      const u16x8 h1 = *(const u16x8*)&sm[E_HO + (wr2 * 32 + 16 + l15) * E_HS + k];
      a20 = MF(h0, b2f[s], a20);
      a21 = MF(h1, b2f[s], a21);
    }
    {
      float* ob = (float*)sm;  // overlays x region (safe after B2)
#pragma unroll
      for (int reg = 0; reg < 4; reg++) {
        const int row0 = wr2 * 32 + 4 * g + reg;
        ob[row0 * 64 + wc2 * 16 + l15] = fmaxf(a20[reg] + bias2, 0.f);
        ob[(row0 + 16) * 64 + wc2 * 16 + l15] = fmaxf(a21[reg] + bias2, 0.f);
      }
    }
    __syncthreads();  // B3: ob visible

    // ---- LayerNorm + store (all 512 threads: 64 rows x 8 lanes) ----
    {
      const float* ob = (const float*)sm;
      const int p = t & 7;
      const f4 v0 = *(const f4*)&ob[r * 64 + p * 8];
      const f4 v1 = *(const f4*)&ob[r * 64 + p * 8 + 4];
      float s = 0.f, s2 = 0.f;
#pragma unroll
      for (int j = 0; j < 4; j++) {
        s += v0[j] + v1[j];
        s2 += v0[j] * v0[j] + v1[j] * v1[j];
      }
      s += __shfl_xor(s, 1);  s += __shfl_xor(s, 2);  s += __shfl_xor(s, 4);
      s2 += __shfl_xor(s2, 1); s2 += __shfl_xor(s2, 2); s2 += __shfl_xor(s2, 4);
      const float mu = s * (1.f / 64.f);
      const float var = s2 * (1.f / 64.f) - mu * mu;
      const float rstd = rsqrtf(var + 1e-5f);
      const f4 ga0 = *(const f4*)&gamma[p * 8];
      const f4 ga1 = *(const f4*)&gamma[p * 8 + 4];
      const f4 be0 = *(const f4*)&beta[p * 8];
      const f4 be1 = *(const f4*)&beta[p * 8 + 4];
      f4 o0, o1;
#pragma unroll
      for (int j = 0; j < 4; j++) {
        o0[j] = (v0[j] - mu) * rstd * ga0[j] + be0[j];
        o1[j] = (v1[j] - mu) * rstd * ga1[j] + be1[j];
      }
      float* op = edge_out + ((size_t)tile * 64 + r) * 64 + p * 8;
      *(f4*)op = o0;           // cached store: node kernel re-reads via L3
      *(f4*)(op + 4) = o1;
    }
  }
#undef IDX
#undef ROWS
}

// ---- node kernel LDS (u16): 64-row tiles, ob overlays x ----
// x: 64x128 stride 136 -> [0,8704); h: [8704,17408); ob f32 aliases sm[0..8192)
// total 17408 u16 = 34816 B -> 4 blocks/CU
#define N_XS 136
#define N_HO 8704

__global__ __launch_bounds__(512, 8)
void node_mlp_kernel(const u16* __restrict__ nh,
                     const float* __restrict__ edge_out,
                     const int* __restrict__ offsets,
                     const int* __restrict__ elist,
                     const float* __restrict__ W1, const float* __restrict__ b1,
                     const float* __restrict__ W2, const float* __restrict__ b2,
                     const float* __restrict__ gamma, const float* __restrict__ beta,
                     float* __restrict__ node_out, int ntiles) {
  __shared__ __align__(16) u16 sm[17408];
  const int t = threadIdx.x;
  const int wid = t >> 6, lane = t & 63, g = lane >> 4, l15 = lane & 15;
  const int wr1 = wid >> 2, wc1 = wid & 3;
  const int wr2 = wid & 1, wc2 = wid >> 1;

  u16x8 b1f[4][2], b2f[4];
#pragma unroll
  for (int s = 0; s < 4; s++)
#pragma unroll
    for (int ci = 0; ci < 2; ci++) {
      const int col = wc1 * 32 + ci * 16 + l15;
      u16x8 th;
#pragma unroll
      for (int i = 0; i < 8; i++) th[i] = f2h(W1[(s * 32 + g * 8 + i) * 128 + col]);
      b1f[s][ci] = th;
    }
#pragma unroll
  for (int s = 0; s < 4; s++) {
    const int col = wc2 * 16 + l15;
    u16x8 th;
#pragma unroll
    for (int i = 0; i < 8; i++) th[i] = f2h(W2[(s * 32 + g * 8 + i) * 64 + col]);
    b2f[s] = th;
  }
  const float bias1_0 = b1[wc1 * 32 + l15];
  const float bias1_1 = b1[wc1 * 32 + 16 + l15];
  const float bias2 = b2[wc2 * 16 + l15];

  const int r = t >> 3, q = t & 7;

  for (int tile = blockIdx.x; tile < ntiles; tile += gridDim.x) {
    const long nbase = (long)tile * 64;
    __syncthreads();  // B0: prior LN ob-reads done (ob aliases x region)

    // ---- gather x = [node_attr(f16) | csr-sum(edge_out)] ----
    {
      const long n = nbase + r;
      u16x8 ha = {0, 0, 0, 0, 0, 0, 0, 0};
      float ac[8];
#pragma unroll
      for (int j = 0; j < 8; j++) ac[j] = 0.f;
      if (n < NN) {
        ha = *(const u16x8*)&nh[(size_t)n * 64 + q * 8];
        const int o0 = offsets[n], o1 = offsets[n + 1];
        int i = o0;
        for (; i + 4 <= o1; i += 4) {
          int e[4];
#pragma unroll
          for (int j = 0; j < 4; j++) e[j] = elist[i + j];
          f4 u0[4], u1[4];
#pragma unroll
          for (int j = 0; j < 4; j++) {
            u0[j] = *(const f4*)&edge_out[(size_t)e[j] * 64 + q * 8];
            u1[j] = *(const f4*)&edge_out[(size_t)e[j] * 64 + q * 8 + 4];
          }
#pragma unroll
          for (int j = 0; j < 4; j++)
#pragma unroll
            for (int k = 0; k < 4; k++) {
              ac[k] += u0[j][k];
              ac[k + 4] += u1[j][k];
            }
        }
        for (; i < o1; i++) {
          const int e = elist[i];
          const f4 u0 = *(const f4*)&edge_out[(size_t)e * 64 + q * 8];
          const f4 u1 = *(const f4*)&edge_out[(size_t)e * 64 + q * 8 + 4];
#pragma unroll
          for (int j = 0; j < 4; j++) {
            ac[j] += u0[j];
            ac[j + 4] += u1[j];
          }
        }
      }
      u16x8 hb;
#pragma unroll
      for (int j = 0; j < 8; j++) hb[j] = f2h(ac[j]);
      *(u16x8*)&sm[r * N_XS + q * 8] = ha;
      *(u16x8*)&sm[r * N_XS + 64 + q * 8] = hb;
    }
    __syncthreads();  // B1: x visible

    // ---- layer 1 ----
    f4 acc00 = {0.f, 0.f, 0.f, 0.f}, acc01 = {0.f, 0.f, 0.f, 0.f};
    f4 acc10 = {0.f, 0.f, 0.f, 0.f}, acc11 = {0.f, 0.f, 0.f, 0.f};
#pragma unroll
    for (int s = 0; s < 4; s++) {
      const int k = s * 32 + g * 8;
      const u16x8 a0 = *(const u16x8*)&sm[(wr1 * 32 + l15) * N_XS + k];
      const u16x8 a1 = *(const u16x8*)&sm[(wr1 * 32 + 16 + l15) * N_XS + k];
      acc00 = MF(a0, b1f[s][0], acc00);
      acc01 = MF(a0, b1f[s][1], acc01);
      acc10 = MF(a1, b1f[s][0], acc10);
      acc11 = MF(a1, b1f[s][1], acc11);
    }
#pragma unroll
    for (int reg = 0; reg < 4; reg++) {
      const int row0 = wr1 * 32 + 4 * g + reg;
      const int row1 = row0 + 16;
      sm[N_HO + row0 * N_XS + wc1 * 32 + l15] = f2h(fmaxf(acc00[reg] + bias1_0, 0.f));
      sm[N_HO + row0 * N_XS + wc1 * 32 + 16 + l15] = f2h(fmaxf(acc01[reg] + bias1_1, 0.f));
      sm[N_HO + row1 * N_XS + wc1 * 32 + l15] = f2h(fmaxf(acc10[reg] + bias1_0, 0.f));
      sm[N_HO + row1 * N_XS + wc1 * 32 + 16 + l15] = f2h(fmaxf(acc11[reg] + bias1_1, 0.f));
    }
    __syncthreads();  // B2: h visible; all x-reads complete

    // ---- layer 2 ----
    f4 a20 = {0.f, 0.f, 0.f, 0.f}, a21 = {0.f, 0.f, 0.f, 0.f};
#pragma unroll
    for (int s = 0; s < 4; s++) {
      const int k = s * 32 + g * 8;
      const u16x8 h0 = *(const u16x8*)&sm[N_HO + (wr2 * 32 + l15) * N_XS + k];
      const u16x8 h1 = *(const u16x8*)&sm[N_HO + (wr2 * 32 + 16 + l15) * N_XS + k];
      a20 = MF(h0, b2f[s], a20);
      a21 = MF(h1, b2f[s], a21);
    }
    {
      float* ob = (float*)sm;  // overlays x region (safe after B2)
#pragma unroll
      for (int reg = 0; reg < 4; reg++) {
        const int row0 = wr2 * 32 + 4 * g + reg;
        ob[row0 * 64 + wc2 * 16 + l15] = fmaxf(a20[reg] + bias2, 0.f);
        ob[(row0 + 16) * 64 + wc2 * 16 + l15] = fmaxf(a21[reg] + bias2, 0.f);
      }
    }
    __syncthreads();  // B3: ob visible

    // ---- LayerNorm + store ----
    {
      const float* ob = (const float*)sm;
      const int p = t & 7;
      const f4 v0 = *(const f4*)&ob[r * 64 + p * 8];
      const f4 v1 = *(const f4*)&ob[r * 64 + p * 8 + 4];
      float s = 0.f, s2 = 0.f;
#pragma unroll
      for (int j = 0; j < 4; j++) {
        s += v0[j] + v1[j];
        s2 += v0[j] * v0[j] + v1[j] * v1[j];
      }
      s += __shfl_xor(s, 1);  s += __shfl_xor(s, 2);  s += __shfl_xor(s, 4);
      s2 += __shfl_xor(s2, 1); s2 += __shfl_xor(s2, 2); s2 += __shfl_xor(s2, 4);
      const float mu = s * (1.f / 64.f);
      const float var = s2 * (1.f / 64.f) - mu * mu;
      const float rstd = rsqrtf(var + 1e-5f);
      const long n = nbase + r;
      if (n < NN) {
        const f4 ga0 = *(const f4*)&gamma[p * 8];
        const f4 ga1 = *(const f4*)&gamma[p * 8 + 4];
        const f4 be0 = *(const f4*)&beta[p * 8];
        const f4 be1 = *(const f4*)&beta[p * 8 + 4];
        f4 o0, o1;
#pragma unroll
        for (int j = 0; j < 4; j++) {
          o0[j] = (v0[j] - mu) * rstd * ga0[j] + be0[j];
          o1[j] = (v1[j] - mu) * rstd * ga1[j] + be1[j];
        }
        float* op = node_out + (size_t)n * 64 + p * 8;
        __builtin_nontemporal_store(o0, (f4*)op);
        __builtin_nontemporal_store(o1, (f4*)(op + 4));
      }
    }
  }
}

extern "C" void kernel_launch(void* const* d_in, const int* in_sizes, int n_in,
                              void* d_out, int out_size, void* d_ws, size_t ws_size,
                              hipStream_t stream) {
  const float* edge_attr = (const float*)d_in[0];
  const float* node_attr = (const float*)d_in[1];
  const int* eidx = (const int*)d_in[2];
  // d_in[3] = batch (unused)
  const float* eW1 = (const float*)d_in[4];
  const float* eb1 = (const float*)d_in[5];
  const float* eW2 = (const float*)d_in[6];
  const float* eb2 = (const float*)d_in[7];
  const float* eg = (const float*)d_in[8];
  const float* ebt = (const float*)d_in[9];
  const float* nW1 = (const float*)d_in[10];
  const float* nb1 = (const float*)d_in[11];
  const float* nW2 = (const float*)d_in[12];
  const float* nb2 = (const float*)d_in[13];
  const float* ng = (const float*)d_in[14];
  const float* nbt = (const float*)d_in[15];

  float* out_edge = (float*)d_out;
  float* out_node = out_edge + (size_t)NE * 64;

  // workspace: nh (f16 node_attr, 6.4 MB) then CSR ints
  u16* nh = (u16*)d_ws;
  int* deg = (int*)((char*)d_ws + (size_t)NN * 64 * 2);
  int* offsets = deg + NN;
  int* cur = offsets + NN + 1;
  int* elist = cur + NN;

  const int n4 = NN * 64 / 4;
  cvt_kernel<<<(n4 + 255) / 256, 256, 0, stream>>>(node_attr, nh, n4);
  zero_int_kernel<<<(NN + 255) / 256, 256, 0, stream>>>(deg, NN);
  hist_kernel<<<(NE + 255) / 256, 256, 0, stream>>>(eidx, deg);
  scan_kernel<<<1, 1024, 0, stream>>>(deg, offsets, cur);
  scatter_kernel<<<(NE + 255) / 256, 256, 0, stream>>>(eidx, cur, elist);

  const int etiles = NE / 64;         // 12500
  const int ntiles = (NN + 63) / 64;  // 782
  edge_mlp_kernel<<<768, 512, 0, stream>>>(edge_attr, nh, eidx,
                                           eW1, eb1, eW2, eb2, eg, ebt,
                                           out_edge, etiles);
  node_mlp_kernel<<<ntiles, 512, 0, stream>>>(nh, out_edge, offsets, elist,
                                              nW1, nb1, nW2, nb2, ng, nbt,
                                              out_node, ntiles);
}

// Round 15
// 570.143 us; speedup vs baseline: 1.1284x; 1.1284x over previous
//
#include <hip/hip_runtime.h>

typedef float f4 __attribute__((ext_vector_type(4)));
typedef _Float16 f16;
typedef f16 f16x8 __attribute__((ext_vector_type(8)));
typedef unsigned short u16;
typedef u16 u16x4 __attribute__((ext_vector_type(4)));
typedef u16 u16x8 __attribute__((ext_vector_type(8)));

#define NE 800000
#define NN 50000

static __device__ __forceinline__ f4 MF(u16x8 a, u16x8 b, f4 c) {
  return __builtin_amdgcn_mfma_f32_16x16x32_f16(
      __builtin_bit_cast(f16x8, a), __builtin_bit_cast(f16x8, b), c, 0, 0, 0);
}
static __device__ __forceinline__ u16 f2h(float x) {
  return __builtin_bit_cast(u16, (f16)x);
}

// ---------------- prologue kernels (proven) ----------------
__global__ void cvt_kernel(const float* __restrict__ na, u16* __restrict__ nh,
                           int n4) {
  int i = blockIdx.x * blockDim.x + threadIdx.x;
  if (i < n4) {
    const f4 v = ((const f4*)na)[i];
    u16x4 h;
#pragma unroll
    for (int j = 0; j < 4; j++) h[j] = f2h(v[j]);
    ((u16x4*)nh)[i] = h;
  }
}

__global__ void zero_int_kernel(int* __restrict__ p, int n) {
  int i = blockIdx.x * blockDim.x + threadIdx.x;
  if (i < n) p[i] = 0;
}

__global__ void hist_kernel(const int* __restrict__ eidx, int* __restrict__ deg) {
  int e = blockIdx.x * blockDim.x + threadIdx.x;
  if (e < NE) atomicAdd(&deg[eidx[NE + e]], 1);
}

__global__ __launch_bounds__(1024)
void scan_kernel(const int* __restrict__ deg, int* __restrict__ offsets,
                 int* __restrict__ cur) {
  __shared__ int buf[2][1024];
  const int t = threadIdx.x;
  const int CH = (NN + 1023) / 1024;  // 49
  const int s = t * CH;
  const int e = (s + CH < NN) ? s + CH : NN;
  int sum = 0;
  for (int i = s; i < e; i++) sum += deg[i];
  buf[0][t] = sum;
  __syncthreads();
  int src = 0;
  for (int d = 1; d < 1024; d <<= 1) {
    int v = buf[src][t];
    if (t >= d) v += buf[src][t - d];
    buf[src ^ 1][t] = v;
    src ^= 1;
    __syncthreads();
  }
  int run = buf[src][t] - sum;  // exclusive prefix
  for (int i = s; i < e; i++) {
    offsets[i] = run;
    cur[i] = run;
    run += deg[i];
  }
  if (e == NN) offsets[NN] = run;
}

__global__ void scatter_kernel(const int* __restrict__ eidx, int* __restrict__ cur,
                               int* __restrict__ elist) {
  int e = blockIdx.x * blockDim.x + threadIdx.x;
  if (e < NE) {
    int slot = atomicAdd(&cur[eidx[NE + e]], 1);
    elist[slot] = e;
  }
}

// ---- edge kernel LDS (u16 units): 64-row tiles, ob overlays x ----
// x: 64 x 192, stride 200 -> [0, 12800)
// h: 64 x 128, stride 136 -> [12800, 21504)
// ob: f32 64x64 aliases sm[0..8192) u16  (x dead after B2)
#define E_XS 200
#define E_HS 136
#define E_HO 12800

__global__ __launch_bounds__(512, 4)
void edge_mlp_kernel(const float* __restrict__ edge_attr,
                     const u16* __restrict__ nh,
                     const int* __restrict__ eidx,
                     const float* __restrict__ W1, const float* __restrict__ b1,
                     const float* __restrict__ W2, const float* __restrict__ b2,
                     const float* __restrict__ gamma, const float* __restrict__ beta,
                     float* __restrict__ edge_out, int ntiles) {
  __shared__ __align__(16) u16 sm[21504];
  const int t = threadIdx.x;
  const int wid = t >> 6, lane = t & 63, g = lane >> 4, l15 = lane & 15;
  const int wr1 = wid >> 2, wc1 = wid & 3;  // L1: 32 rows x 32 cols per wave
  const int wr2 = wid & 1, wc2 = wid >> 1;  // L2: 32 rows x 16 cols per wave

  u16x8 b1f[6][2], b2f[4];
#pragma unroll
  for (int s = 0; s < 6; s++)
#pragma unroll
    for (int ci = 0; ci < 2; ci++) {
      const int col = wc1 * 32 + ci * 16 + l15;
      u16x8 th;
#pragma unroll
      for (int i = 0; i < 8; i++) th[i] = f2h(W1[(s * 32 + g * 8 + i) * 128 + col]);
      b1f[s][ci] = th;
    }
#pragma unroll
  for (int s = 0; s < 4; s++) {
    const int col = wc2 * 16 + l15;
    u16x8 th;
#pragma unroll
    for (int i = 0; i < 8; i++) th[i] = f2h(W2[(s * 32 + g * 8 + i) * 64 + col]);
    b2f[s] = th;
  }
  const float bias1_0 = b1[wc1 * 32 + l15];
  const float bias1_1 = b1[wc1 * 32 + 16 + l15];
  const float bias2 = b2[wc2 * 16 + l15];

  const int r = t >> 3;
  const int c8 = (t & 7) * 8;

  // two independent prefetch pipelines (sets A and B), each = round-13's
  // proven pipeline with stride 2G; bodies interleave A,B to double MLP.
  int idxrA, idxsA, idxrB, idxsB;
  u16x8 grecvA, gsendA, grecvB, gsendB;
  f4 ge0A, ge1A, ge0B, ge1B;

#define IDXL(S, TB)                                            \
  {                                                            \
    const long e_ = (long)(TB)*64 + r;                         \
    idxr##S = eidx[NE + e_];                                   \
    idxs##S = eidx[e_];                                        \
  }
#define ROWSL(S, TB)                                           \
  {                                                            \
    grecv##S = *(const u16x8*)&nh[(size_t)idxr##S * 64 + c8];  \
    gsend##S = *(const u16x8*)&nh[(size_t)idxs##S * 64 + c8];  \
    const float* ep_ =                                         \
        &edge_attr[((size_t)(TB)*64 + r) * 64 + c8];           \
    ge0##S = __builtin_nontemporal_load((const f4*)ep_);       \
    ge1##S = __builtin_nontemporal_load((const f4*)(ep_ + 4)); \
  }
#define CL(X) ((X) > last ? last : (X))

  const int G = gridDim.x;
  const int G2 = 2 * G;
  const int last = ntiles - 1;
  IDXL(A, CL((int)blockIdx.x));
  ROWSL(A, CL((int)blockIdx.x));
  IDXL(A, CL((int)blockIdx.x + G2));
  IDXL(B, CL((int)blockIdx.x + G));
  ROWSL(B, CL((int)blockIdx.x + G));
  IDXL(B, CL((int)blockIdx.x + G + G2));

#define BODY(S, TILE)                                                          \
  {                                                                            \
    const int tile_ = (TILE);                                                  \
    __syncthreads(); /* B0: prior LN ob-reads done (ob aliases x) */           \
    *(u16x8*)&sm[r * E_XS + c8] = grecv##S;                                    \
    *(u16x8*)&sm[r * E_XS + 64 + c8] = gsend##S;                               \
    {                                                                          \
      u16x8 he;                                                                \
      _Pragma("unroll") for (int j = 0; j < 4; j++) {                          \
        he[j] = f2h(ge0##S[j]);                                                \
        he[4 + j] = f2h(ge1##S[j]);                                            \
      }                                                                        \
      *(u16x8*)&sm[r * E_XS + 128 + c8] = he;                                  \
    }                                                                          \
    __syncthreads(); /* B1: x visible */                                       \
    ROWSL(S, CL(tile_ + G2));                                                  \
    IDXL(S, CL(tile_ + 2 * G2));                                               \
    f4 acc00 = {0.f, 0.f, 0.f, 0.f}, acc01 = {0.f, 0.f, 0.f, 0.f};            \
    f4 acc10 = {0.f, 0.f, 0.f, 0.f}, acc11 = {0.f, 0.f, 0.f, 0.f};            \
    _Pragma("unroll") for (int s = 0; s < 6; s++) {                            \
      const int k = s * 32 + g * 8;                                            \
      const u16x8 a0 = *(const u16x8*)&sm[(wr1 * 32 + l15) * E_XS + k];        \
      const u16x8 a1 = *(const u16x8*)&sm[(wr1 * 32 + 16 + l15) * E_XS + k];   \
      acc00 = MF(a0, b1f[s][0], acc00);                                        \
      acc01 = MF(a0, b1f[s][1], acc01);                                        \
      acc10 = MF(a1, b1f[s][0], acc10);                                        \
      acc11 = MF(a1, b1f[s][1], acc11);                                        \
    }                                                                          \
    _Pragma("unroll") for (int reg = 0; reg < 4; reg++) {                      \
      const int row0 = wr1 * 32 + 4 * g + reg;                                 \
      const int row1 = row0 + 16;                                              \
      sm[E_HO + row0 * E_HS + wc1 * 32 + l15] =                                \
          f2h(fmaxf(acc00[reg] + bias1_0, 0.f));                               \
      sm[E_HO + row0 * E_HS + wc1 * 32 + 16 + l15] =                           \
          f2h(fmaxf(acc01[reg] + bias1_1, 0.f));                               \
      sm[E_HO + row1 * E_HS + wc1 * 32 + l15] =                                \
          f2h(fmaxf(acc10[reg] + bias1_0, 0.f));                               \
      sm[E_HO + row1 * E_HS + wc1 * 32 + 16 + l15] =                           \
          f2h(fmaxf(acc11[reg] + bias1_1, 0.f));                               \
    }                                                                          \
    __syncthreads(); /* B2: h visible; x dead -> ob may overlay */             \
    f4 a20 = {0.f, 0.f, 0.f, 0.f}, a21 = {0.f, 0.f, 0.f, 0.f};                \
    _Pragma("unroll") for (int s = 0; s < 4; s++) {                            \
      const int k = s * 32 + g * 8;                                            \
      const u16x8 h0 = *(const u16x8*)&sm[E_HO + (wr2 * 32 + l15) * E_HS + k]; \
      const u16x8 h1 =                                                         \
          *(const u16x8*)&sm[E_HO + (wr2 * 32 + 16 + l15) * E_HS + k];         \
      a20 = MF(h0, b2f[s], a20);                                               \
      a21 = MF(h1, b2f[s], a21);                                               \
    }                                                                          \
    {                                                                          \
      float* ob = (float*)sm;                                                  \
      _Pragma("unroll") for (int reg = 0; reg < 4; reg++) {                    \
        const int row0 = wr2 * 32 + 4 * g + reg;                               \
        ob[row0 * 64 + wc2 * 16 + l15] = fmaxf(a20[reg] + bias2, 0.f);         \
        ob[(row0 + 16) * 64 + wc2 * 16 + l15] = fmaxf(a21[reg] + bias2, 0.f);  \
      }                                                                        \
    }                                                                          \
    __syncthreads(); /* B3: ob visible */                                      \
    {                                                                          \
      const float* ob = (const float*)sm;                                      \
      const int p = t & 7;                                                     \
      const f4 v0 = *(const f4*)&ob[r * 64 + p * 8];                           \
      const f4 v1 = *(const f4*)&ob[r * 64 + p * 8 + 4];                       \
      float s_ = 0.f, s2_ = 0.f;                                               \
      _Pragma("unroll") for (int j = 0; j < 4; j++) {                          \
        s_ += v0[j] + v1[j];                                                   \
        s2_ += v0[j] * v0[j] + v1[j] * v1[j];                                  \
      }                                                                        \
      s_ += __shfl_xor(s_, 1);                                                 \
      s_ += __shfl_xor(s_, 2);                                                 \
      s_ += __shfl_xor(s_, 4);                                                 \
      s2_ += __shfl_xor(s2_, 1);                                               \
      s2_ += __shfl_xor(s2_, 2);                                               \
      s2_ += __shfl_xor(s2_, 4);                                               \
      const float mu = s_ * (1.f / 64.f);                                      \
      const float var = s2_ * (1.f / 64.f) - mu * mu;                          \
      const float rstd = rsqrtf(var + 1e-5f);                                  \
      const f4 ga0 = *(const f4*)&gamma[p * 8];                                \
      const f4 ga1 = *(const f4*)&gamma[p * 8 + 4];                            \
      const f4 be0 = *(const f4*)&beta[p * 8];                                 \
      const f4 be1 = *(const f4*)&beta[p * 8 + 4];                             \
      f4 o0, o1;                                                               \
      _Pragma("unroll") for (int j = 0; j < 4; j++) {                          \
        o0[j] = (v0[j] - mu) * rstd * ga0[j] + be0[j];                         \
        o1[j] = (v1[j] - mu) * rstd * ga1[j] + be1[j];                         \
      }                                                                        \
      float* op = edge_out + ((size_t)tile_ * 64 + r) * 64 + p * 8;            \
      *(f4*)op = o0;                                                           \
      *(f4*)(op + 4) = o1;                                                     \
    }                                                                          \
  }

  for (int tile = blockIdx.x; tile < ntiles; tile += G2) {
    BODY(A, tile);
    const int tileB = tile + G;
    if (tileB < ntiles) {
      BODY(B, tileB);
    }
  }
#undef BODY
#undef CL
#undef IDXL
#undef ROWSL
}

// ---- node kernel LDS (u16): 64-row tiles (round-13 proven) ----
#define N_XS 136
#define N_HO 8704
#define N_OB 17408

__global__ __launch_bounds__(512, 4)
void node_mlp_kernel(const u16* __restrict__ nh,
                     const float* __restrict__ edge_out,
                     const int* __restrict__ offsets,
                     const int* __restrict__ elist,
                     const float* __restrict__ W1, const float* __restrict__ b1,
                     const float* __restrict__ W2, const float* __restrict__ b2,
                     const float* __restrict__ gamma, const float* __restrict__ beta,
                     float* __restrict__ node_out, int ntiles) {
  __shared__ __align__(16) u16 sm[25600];
  const int t = threadIdx.x;
  const int wid = t >> 6, lane = t & 63, g = lane >> 4, l15 = lane & 15;
  const int wr1 = wid >> 2, wc1 = wid & 3;
  const int wr2 = wid & 1, wc2 = wid >> 1;

  u16x8 b1f[4][2], b2f[4];
#pragma unroll
  for (int s = 0; s < 4; s++)
#pragma unroll
    for (int ci = 0; ci < 2; ci++) {
      const int col = wc1 * 32 + ci * 16 + l15;
      u16x8 th;
#pragma unroll
      for (int i = 0; i < 8; i++) th[i] = f2h(W1[(s * 32 + g * 8 + i) * 128 + col]);
      b1f[s][ci] = th;
    }
#pragma unroll
  for (int s = 0; s < 4; s++) {
    const int col = wc2 * 16 + l15;
    u16x8 th;
#pragma unroll
    for (int i = 0; i < 8; i++) th[i] = f2h(W2[(s * 32 + g * 8 + i) * 64 + col]);
    b2f[s] = th;
  }
  const float bias1_0 = b1[wc1 * 32 + l15];
  const float bias1_1 = b1[wc1 * 32 + 16 + l15];
  const float bias2 = b2[wc2 * 16 + l15];

  const int r = t >> 3, q = t & 7;

  for (int tile = blockIdx.x; tile < ntiles; tile += gridDim.x) {
    const long nbase = (long)tile * 64;
    __syncthreads();  // protect LDS across iterations

    // ---- gather x = [node_attr(f16) | csr-sum(edge_out)] ----
    {
      const long n = nbase + r;
      u16x8 ha = {0, 0, 0, 0, 0, 0, 0, 0};
      float ac[8];
#pragma unroll
      for (int j = 0; j < 8; j++) ac[j] = 0.f;
      if (n < NN) {
        ha = *(const u16x8*)&nh[(size_t)n * 64 + q * 8];
        const int o0 = offsets[n], o1 = offsets[n + 1];
        int i = o0;
        for (; i + 4 <= o1; i += 4) {
          int e[4];
#pragma unroll
          for (int j = 0; j < 4; j++) e[j] = elist[i + j];
          f4 u0[4], u1[4];
#pragma unroll
          for (int j = 0; j < 4; j++) {
            u0[j] = *(const f4*)&edge_out[(size_t)e[j] * 64 + q * 8];
            u1[j] = *(const f4*)&edge_out[(size_t)e[j] * 64 + q * 8 + 4];
          }
#pragma unroll
          for (int j = 0; j < 4; j++)
#pragma unroll
            for (int k = 0; k < 4; k++) {
              ac[k] += u0[j][k];
              ac[k + 4] += u1[j][k];
            }
        }
        for (; i < o1; i++) {
          const int e = elist[i];
          const f4 u0 = *(const f4*)&edge_out[(size_t)e * 64 + q * 8];
          const f4 u1 = *(const f4*)&edge_out[(size_t)e * 64 + q * 8 + 4];
#pragma unroll
          for (int j = 0; j < 4; j++) {
            ac[j] += u0[j];
            ac[j + 4] += u1[j];
          }
        }
      }
      u16x8 hb;
#pragma unroll
      for (int j = 0; j < 8; j++) hb[j] = f2h(ac[j]);
      *(u16x8*)&sm[r * N_XS + q * 8] = ha;
      *(u16x8*)&sm[r * N_XS + 64 + q * 8] = hb;
    }
    __syncthreads();

    // ---- layer 1 ----
    f4 acc00 = {0.f, 0.f, 0.f, 0.f}, acc01 = {0.f, 0.f, 0.f, 0.f};
    f4 acc10 = {0.f, 0.f, 0.f, 0.f}, acc11 = {0.f, 0.f, 0.f, 0.f};
#pragma unroll
    for (int s = 0; s < 4; s++) {
      const int k = s * 32 + g * 8;
      const u16x8 a0 = *(const u16x8*)&sm[(wr1 * 32 + l15) * N_XS + k];
      const u16x8 a1 = *(const u16x8*)&sm[(wr1 * 32 + 16 + l15) * N_XS + k];
      acc00 = MF(a0, b1f[s][0], acc00);
      acc01 = MF(a0, b1f[s][1], acc01);
      acc10 = MF(a1, b1f[s][0], acc10);
      acc11 = MF(a1, b1f[s][1], acc11);
    }
#pragma unroll
    for (int reg = 0; reg < 4; reg++) {
      const int row0 = wr1 * 32 + 4 * g + reg;
      const int row1 = row0 + 16;
      sm[N_HO + row0 * N_XS + wc1 * 32 + l15] = f2h(fmaxf(acc00[reg] + bias1_0, 0.f));
      sm[N_HO + row0 * N_XS + wc1 * 32 + 16 + l15] = f2h(fmaxf(acc01[reg] + bias1_1, 0.f));
      sm[N_HO + row1 * N_XS + wc1 * 32 + l15] = f2h(fmaxf(acc10[reg] + bias1_0, 0.f));
      sm[N_HO + row1 * N_XS + wc1 * 32 + 16 + l15] = f2h(fmaxf(acc11[reg] + bias1_1, 0.f));
    }
    __syncthreads();

    // ---- layer 2 ----
    f4 a20 = {0.f, 0.f, 0.f, 0.f}, a21 = {0.f, 0.f, 0.f, 0.f};
#pragma unroll
    for (int s = 0; s < 4; s++) {
      const int k = s * 32 + g * 8;
      const u16x8 h0 = *(const u16x8*)&sm[N_HO + (wr2 * 32 + l15) * N_XS + k];
      const u16x8 h1 = *(const u16x8*)&sm[N_HO + (wr2 * 32 + 16 + l15) * N_XS + k];
      a20 = MF(h0, b2f[s], a20);
      a21 = MF(h1, b2f[s], a21);
    }
    {
      float* ob = (float*)&sm[N_OB];
#pragma unroll
      for (int reg = 0; reg < 4; reg++) {
        const int row0 = wr2 * 32 + 4 * g + reg;
        ob[row0 * 64 + wc2 * 16 + l15] = fmaxf(a20[reg] + bias2, 0.f);
        ob[(row0 + 16) * 64 + wc2 * 16 + l15] = fmaxf(a21[reg] + bias2, 0.f);
      }
    }
    __syncthreads();

    // ---- LayerNorm + store ----
    {
      const float* ob = (const float*)&sm[N_OB];
      const int p = t & 7;
      const f4 v0 = *(const f4*)&ob[r * 64 + p * 8];
      const f4 v1 = *(const f4*)&ob[r * 64 + p * 8 + 4];
      float s = 0.f, s2 = 0.f;
#pragma unroll
      for (int j = 0; j < 4; j++) {
        s += v0[j] + v1[j];
        s2 += v0[j] * v0[j] + v1[j] * v1[j];
      }
      s += __shfl_xor(s, 1);  s += __shfl_xor(s, 2);  s += __shfl_xor(s, 4);
      s2 += __shfl_xor(s2, 1); s2 += __shfl_xor(s2, 2); s2 += __shfl_xor(s2, 4);
      const float mu = s * (1.f / 64.f);
      const float var = s2 * (1.f / 64.f) - mu * mu;
      const float rstd = rsqrtf(var + 1e-5f);
      const long n = nbase + r;
      if (n < NN) {
        const f4 ga0 = *(const f4*)&gamma[p * 8];
        const f4 ga1 = *(const f4*)&gamma[p * 8 + 4];
        const f4 be0 = *(const f4*)&beta[p * 8];
        const f4 be1 = *(const f4*)&beta[p * 8 + 4];
        f4 o0, o1;
#pragma unroll
        for (int j = 0; j < 4; j++) {
          o0[j] = (v0[j] - mu) * rstd * ga0[j] + be0[j];
          o1[j] = (v1[j] - mu) * rstd * ga1[j] + be1[j];
        }
        float* op = node_out + (size_t)n * 64 + p * 8;
        __builtin_nontemporal_store(o0, (f4*)op);
        __builtin_nontemporal_store(o1, (f4*)(op + 4));
      }
    }
  }
}

extern "C" void kernel_launch(void* const* d_in, const int* in_sizes, int n_in,
                              void* d_out, int out_size, void* d_ws, size_t ws_size,
                              hipStream_t stream) {
  const float* edge_attr = (const float*)d_in[0];
  const float* node_attr = (const float*)d_in[1];
  const int* eidx = (const int*)d_in[2];
  // d_in[3] = batch (unused)
  const float* eW1 = (const float*)d_in[4];
  const float* eb1 = (const float*)d_in[5];
  const float* eW2 = (const float*)d_in[6];
  const float* eb2 = (const float*)d_in[7];
  const float* eg = (const float*)d_in[8];
  const float* ebt = (const float*)d_in[9];
  const float* nW1 = (const float*)d_in[10];
  const float* nb1 = (const float*)d_in[11];
  const float* nW2 = (const float*)d_in[12];
  const float* nb2 = (const float*)d_in[13];
  const float* ng = (const float*)d_in[14];
  const float* nbt = (const float*)d_in[15];

  float* out_edge = (float*)d_out;
  float* out_node = out_edge + (size_t)NE * 64;

  // workspace: nh (f16 node_attr, 6.4 MB) then CSR ints
  u16* nh = (u16*)d_ws;
  int* deg = (int*)((char*)d_ws + (size_t)NN * 64 * 2);
  int* offsets = deg + NN;
  int* cur = offsets + NN + 1;
  int* elist = cur + NN;

  const int n4 = NN * 64 / 4;
  cvt_kernel<<<(n4 + 255) / 256, 256, 0, stream>>>(node_attr, nh, n4);
  zero_int_kernel<<<(NN + 255) / 256, 256, 0, stream>>>(deg, NN);
  hist_kernel<<<(NE + 255) / 256, 256, 0, stream>>>(eidx, deg);
  scan_kernel<<<1, 1024, 0, stream>>>(deg, offsets, cur);
  scatter_kernel<<<(NE + 255) / 256, 256, 0, stream>>>(eidx, cur, elist);

  const int etiles = NE / 64;         // 12500
  const int ntiles = (NN + 63) / 64;  // 782
  edge_mlp_kernel<<<768, 512, 0, stream>>>(edge_attr, nh, eidx,
                                           eW1, eb1, eW2, eb2, eg, ebt,
                                           out_edge, etiles);
  node_mlp_kernel<<<ntiles, 512, 0, stream>>>(nh, out_edge, offsets, elist,
                                              nW1, nb1, nW2, nb2, ng, nbt,
                                              out_node, ntiles);
}

// Round 17
// 421.100 us; speedup vs baseline: 1.5278x; 1.3539x over previous
//
#include <hip/hip_runtime.h>

typedef float f4 __attribute__((ext_vector_type(4)));
typedef _Float16 f16;
typedef f16 f16x8 __attribute__((ext_vector_type(8)));
typedef unsigned short u16;
typedef u16 u16x4 __attribute__((ext_vector_type(4)));
typedef u16 u16x8 __attribute__((ext_vector_type(8)));

#define NE 800000
#define NN 50000

static __device__ __forceinline__ f4 MF(u16x8 a, u16x8 b, f4 c) {
  return __builtin_amdgcn_mfma_f32_16x16x32_f16(
      __builtin_bit_cast(f16x8, a), __builtin_bit_cast(f16x8, b), c, 0, 0, 0);
}
static __device__ __forceinline__ u16 f2h(float x) {
  return __builtin_bit_cast(u16, (f16)x);
}

// ---------------- prologue kernels ----------------
// cvt also zeroes deg (saves one launch; hist runs after on same stream)
__global__ void cvt_kernel(const float* __restrict__ na, u16* __restrict__ nh,
                           int* __restrict__ deg, int n4) {
  int i = blockIdx.x * blockDim.x + threadIdx.x;
  if (i < n4) {
    const f4 v = ((const f4*)na)[i];
    u16x4 h;
#pragma unroll
    for (int j = 0; j < 4; j++) h[j] = f2h(v[j]);
    ((u16x4*)nh)[i] = h;
  }
  if (i < NN) deg[i] = 0;
}

__global__ void hist_kernel(const int* __restrict__ eidx, int* __restrict__ deg) {
  int e = blockIdx.x * blockDim.x + threadIdx.x;
  if (e < NE) atomicAdd(&deg[eidx[NE + e]], 1);
}

__global__ __launch_bounds__(1024)
void scan_kernel(const int* __restrict__ deg, int* __restrict__ offsets,
                 int* __restrict__ cur) {
  __shared__ int buf[2][1024];
  const int t = threadIdx.x;
  const int CH = (NN + 1023) / 1024;  // 49
  const int s = t * CH;
  const int e = (s + CH < NN) ? s + CH : NN;
  int sum = 0;
  for (int i = s; i < e; i++) sum += deg[i];
  buf[0][t] = sum;
  __syncthreads();
  int src = 0;
  for (int d = 1; d < 1024; d <<= 1) {
    int v = buf[src][t];
    if (t >= d) v += buf[src][t - d];
    buf[src ^ 1][t] = v;
    src ^= 1;
    __syncthreads();
  }
  int run = buf[src][t] - sum;  // exclusive prefix
  for (int i = s; i < e; i++) {
    offsets[i] = run;
    cur[i] = run;
    run += deg[i];
  }
  if (e == NN) offsets[NN] = run;
}

__global__ void scatter_kernel(const int* __restrict__ eidx, int* __restrict__ cur,
                               int* __restrict__ elist) {
  int e = blockIdx.x * blockDim.x + threadIdx.x;
  if (e < NE) {
    int slot = atomicAdd(&cur[eidx[NE + e]], 1);
    elist[slot] = e;
  }
}

// ---- edge kernel LDS (u16 units): 64-row tiles (round-13 proven, exact) ----
// x: 64 x 192, stride 200 -> [0, 12800)
// h: 64 x 128, stride 136 -> [12800, 21504)
// ob: f32 64x64 @ u16 ofs 21504 (8192 u16) -> total 29696 u16 = 59392 B
#define E_XS 200
#define E_HS 136
#define E_HO 12800
#define E_OB 21504

__global__ __launch_bounds__(512, 4)
void edge_mlp_kernel(const float* __restrict__ edge_attr,
                     const u16* __restrict__ nh,
                     const int* __restrict__ eidx,
                     const float* __restrict__ W1, const float* __restrict__ b1,
                     const float* __restrict__ W2, const float* __restrict__ b2,
                     const float* __restrict__ gamma, const float* __restrict__ beta,
                     float* __restrict__ edge_out, int ntiles) {
  __shared__ __align__(16) u16 sm[29696];
  const int t = threadIdx.x;
  const int wid = t >> 6, lane = t & 63, g = lane >> 4, l15 = lane & 15;
  const int wr1 = wid >> 2, wc1 = wid & 3;  // L1: 32 rows x 32 cols per wave
  const int wr2 = wid & 1, wc2 = wid >> 1;  // L2: 32 rows x 16 cols per wave

  u16x8 b1f[6][2], b2f[4];
#pragma unroll
  for (int s = 0; s < 6; s++)
#pragma unroll
    for (int ci = 0; ci < 2; ci++) {
      const int col = wc1 * 32 + ci * 16 + l15;
      u16x8 th;
#pragma unroll
      for (int i = 0; i < 8; i++) th[i] = f2h(W1[(s * 32 + g * 8 + i) * 128 + col]);
      b1f[s][ci] = th;
    }
#pragma unroll
  for (int s = 0; s < 4; s++) {
    const int col = wc2 * 16 + l15;
    u16x8 th;
#pragma unroll
    for (int i = 0; i < 8; i++) th[i] = f2h(W2[(s * 32 + g * 8 + i) * 64 + col]);
    b2f[s] = th;
  }
  const float bias1_0 = b1[wc1 * 32 + l15];
  const float bias1_1 = b1[wc1 * 32 + 16 + l15];
  const float bias2 = b2[wc2 * 16 + l15];

  const int r = t >> 3;
  const int c8 = (t & 7) * 8;

  int idxr, idxs;
  u16x8 grecv, gsend;
  f4 ge0, ge1;

#define IDX(TB)                                                \
  {                                                            \
    const long e_ = (long)(TB)*64 + r;                         \
    idxr = eidx[NE + e_];                                      \
    idxs = eidx[e_];                                           \
  }
#define ROWS(TB)                                               \
  {                                                            \
    grecv = *(const u16x8*)&nh[(size_t)idxr * 64 + c8];        \
    gsend = *(const u16x8*)&nh[(size_t)idxs * 64 + c8];        \
    const float* ep_ =                                         \
        &edge_attr[((size_t)(TB)*64 + r) * 64 + c8];           \
    ge0 = __builtin_nontemporal_load((const f4*)ep_);          \
    ge1 = __builtin_nontemporal_load((const f4*)(ep_ + 4));    \
  }

  const int G = gridDim.x;
  const int last = ntiles - 1;
  IDX(blockIdx.x);
  ROWS(blockIdx.x);
  {
    int tn = blockIdx.x + G;
    if (tn > last) tn = last;
    IDX(tn);
  }

  for (int tile = blockIdx.x; tile < ntiles; tile += G) {
    // ---- write prefetched x tile -> LDS ----
    *(u16x8*)&sm[r * E_XS + c8] = grecv;
    *(u16x8*)&sm[r * E_XS + 64 + c8] = gsend;
    {
      u16x8 he;
#pragma unroll
      for (int j = 0; j < 4; j++) {
        he[j] = f2h(ge0[j]);
        he[4 + j] = f2h(ge1[j]);
      }
      *(u16x8*)&sm[r * E_XS + 128 + c8] = he;
    }
    __syncthreads();  // B1: x visible

    // ---- issue next tile's rows (indices ready) + indices two ahead ----
    {
      int tn = tile + G;
      if (tn > last) tn = last;
      ROWS(tn);
      int tn2 = tile + 2 * G;
      if (tn2 > last) tn2 = last;
      IDX(tn2);
    }

    // ---- layer 1: per-wave 32x32 tile of h = relu(x @ W1 + b1) ----
    f4 acc00 = {0.f, 0.f, 0.f, 0.f}, acc01 = {0.f, 0.f, 0.f, 0.f};
    f4 acc10 = {0.f, 0.f, 0.f, 0.f}, acc11 = {0.f, 0.f, 0.f, 0.f};
#pragma unroll
    for (int s = 0; s < 6; s++) {
      const int k = s * 32 + g * 8;
      const u16x8 a0 = *(const u16x8*)&sm[(wr1 * 32 + l15) * E_XS + k];
      const u16x8 a1 = *(const u16x8*)&sm[(wr1 * 32 + 16 + l15) * E_XS + k];
      acc00 = MF(a0, b1f[s][0], acc00);
      acc01 = MF(a0, b1f[s][1], acc01);
      acc10 = MF(a1, b1f[s][0], acc10);
      acc11 = MF(a1, b1f[s][1], acc11);
    }
#pragma unroll
    for (int reg = 0; reg < 4; reg++) {
      const int row0 = wr1 * 32 + 4 * g + reg;
      const int row1 = row0 + 16;
      sm[E_HO + row0 * E_HS + wc1 * 32 + l15] = f2h(fmaxf(acc00[reg] + bias1_0, 0.f));
      sm[E_HO + row0 * E_HS + wc1 * 32 + 16 + l15] = f2h(fmaxf(acc01[reg] + bias1_1, 0.f));
      sm[E_HO + row1 * E_HS + wc1 * 32 + l15] = f2h(fmaxf(acc10[reg] + bias1_0, 0.f));
      sm[E_HO + row1 * E_HS + wc1 * 32 + 16 + l15] = f2h(fmaxf(acc11[reg] + bias1_1, 0.f));
    }
    __syncthreads();  // B2: h visible

    // ---- layer 2: per-wave 32x16 tile of o = relu(h @ W2 + b2) ----
    f4 a20 = {0.f, 0.f, 0.f, 0.f}, a21 = {0.f, 0.f, 0.f, 0.f};
#pragma unroll
    for (int s = 0; s < 4; s++) {
      const int k = s * 32 + g * 8;
      const u16x8 h0 = *(const u16x8*)&sm[E_HO + (wr2 * 32 + l15) * E_HS + k];
      const u16x8 h1 = *(const u16x8*)&sm[E_HO + (wr2 * 32 + 16 + l15) * E_HS + k];
      a20 = MF(h0, b2f[s], a20);
      a21 = MF(h1, b2f[s], a21);
    }
    {
      float* ob = (float*)&sm[E_OB];
#pragma unroll
      for (int reg = 0; reg < 4; reg++) {
        const int row0 = wr2 * 32 + 4 * g + reg;
        ob[row0 * 64 + wc2 * 16 + l15] = fmaxf(a20[reg] + bias2, 0.f);
        ob[(row0 + 16) * 64 + wc2 * 16 + l15] = fmaxf(a21[reg] + bias2, 0.f);
      }
    }
    __syncthreads();  // B3: ob visible (also fences x reads before next x write)

    // ---- LayerNorm + store (all 512 threads: 64 rows x 8 lanes) ----
    {
      const float* ob = (const float*)&sm[E_OB];
      const int p = t & 7;
      const f4 v0 = *(const f4*)&ob[r * 64 + p * 8];
      const f4 v1 = *(const f4*)&ob[r * 64 + p * 8 + 4];
      float s = 0.f, s2 = 0.f;
#pragma unroll
      for (int j = 0; j < 4; j++) {
        s += v0[j] + v1[j];
        s2 += v0[j] * v0[j] + v1[j] * v1[j];
      }
      s += __shfl_xor(s, 1);  s += __shfl_xor(s, 2);  s += __shfl_xor(s, 4);
      s2 += __shfl_xor(s2, 1); s2 += __shfl_xor(s2, 2); s2 += __shfl_xor(s2, 4);
      const float mu = s * (1.f / 64.f);
      const float var = s2 * (1.f / 64.f) - mu * mu;
      const float rstd = rsqrtf(var + 1e-5f);
      const f4 ga0 = *(const f4*)&gamma[p * 8];
      const f4 ga1 = *(const f4*)&gamma[p * 8 + 4];
      const f4 be0 = *(const f4*)&beta[p * 8];
      const f4 be1 = *(const f4*)&beta[p * 8 + 4];
      f4 o0, o1;
#pragma unroll
      for (int j = 0; j < 4; j++) {
        o0[j] = (v0[j] - mu) * rstd * ga0[j] + be0[j];
        o1[j] = (v1[j] - mu) * rstd * ga1[j] + be1[j];
      }
      float* op = edge_out + ((size_t)tile * 64 + r) * 64 + p * 8;
      *(f4*)op = o0;           // plain store (d_out write policy: proven r13 form)
      *(f4*)(op + 4) = o1;
    }
  }
#undef IDX
#undef ROWS
}

// ---- node kernel LDS (u16): 64-row tiles (r13 structure; 8-edge unroll) ----
#define N_XS 136
#define N_HO 8704
#define N_OB 17408

__global__ __launch_bounds__(512, 2)
void node_mlp_kernel(const u16* __restrict__ nh,
                     const float* __restrict__ edge_out,
                     const int* __restrict__ offsets,
                     const int* __restrict__ elist,
                     const float* __restrict__ W1, const float* __restrict__ b1,
                     const float* __restrict__ W2, const float* __restrict__ b2,
                     const float* __restrict__ gamma, const float* __restrict__ beta,
                     float* __restrict__ node_out, int ntiles) {
  __shared__ __align__(16) u16 sm[25600];
  const int t = threadIdx.x;
  const int wid = t >> 6, lane = t & 63, g = lane >> 4, l15 = lane & 15;
  const int wr1 = wid >> 2, wc1 = wid & 3;
  const int wr2 = wid & 1, wc2 = wid >> 1;

  u16x8 b1f[4][2], b2f[4];
#pragma unroll
  for (int s = 0; s < 4; s++)
#pragma unroll
    for (int ci = 0; ci < 2; ci++) {
      const int col = wc1 * 32 + ci * 16 + l15;
      u16x8 th;
#pragma unroll
      for (int i = 0; i < 8; i++) th[i] = f2h(W1[(s * 32 + g * 8 + i) * 128 + col]);
      b1f[s][ci] = th;
    }
#pragma unroll
  for (int s = 0; s < 4; s++) {
    const int col = wc2 * 16 + l15;
    u16x8 th;
#pragma unroll
    for (int i = 0; i < 8; i++) th[i] = f2h(W2[(s * 32 + g * 8 + i) * 64 + col]);
    b2f[s] = th;
  }
  const float bias1_0 = b1[wc1 * 32 + l15];
  const float bias1_1 = b1[wc1 * 32 + 16 + l15];
  const float bias2 = b2[wc2 * 16 + l15];

  const int r = t >> 3, q = t & 7;

  for (int tile = blockIdx.x; tile < ntiles; tile += gridDim.x) {
    const long nbase = (long)tile * 64;
    __syncthreads();  // protect LDS across iterations

    // ---- gather x = [node_attr(f16) | csr-sum(edge_out)], 8-deep MLP ----
    {
      const long n = nbase + r;
      u16x8 ha = {0, 0, 0, 0, 0, 0, 0, 0};
      float ac[8];
#pragma unroll
      for (int j = 0; j < 8; j++) ac[j] = 0.f;
      if (n < NN) {
        ha = *(const u16x8*)&nh[(size_t)n * 64 + q * 8];
        const int o0 = offsets[n], o1 = offsets[n + 1];
        int i = o0;
        for (; i + 8 <= o1; i += 8) {
          int e[8];
#pragma unroll
          for (int j = 0; j < 8; j++) e[j] = elist[i + j];
          f4 u0[8], u1[8];
#pragma unroll
          for (int j = 0; j < 8; j++) {
            u0[j] = *(const f4*)&edge_out[(size_t)e[j] * 64 + q * 8];
            u1[j] = *(const f4*)&edge_out[(size_t)e[j] * 64 + q * 8 + 4];
          }
#pragma unroll
          for (int j = 0; j < 8; j++)
#pragma unroll
            for (int k = 0; k < 4; k++) {
              ac[k] += u0[j][k];
              ac[k + 4] += u1[j][k];
            }
        }
        for (; i < o1; i++) {
          const int e = elist[i];
          const f4 u0 = *(const f4*)&edge_out[(size_t)e * 64 + q * 8];
          const f4 u1 = *(const f4*)&edge_out[(size_t)e * 64 + q * 8 + 4];
#pragma unroll
          for (int j = 0; j < 4; j++) {
            ac[j] += u0[j];
            ac[j + 4] += u1[j];
          }
        }
      }
      u16x8 hb;
#pragma unroll
      for (int j = 0; j < 8; j++) hb[j] = f2h(ac[j]);
      *(u16x8*)&sm[r * N_XS + q * 8] = ha;
      *(u16x8*)&sm[r * N_XS + 64 + q * 8] = hb;
    }
    __syncthreads();

    // ---- layer 1 ----
    f4 acc00 = {0.f, 0.f, 0.f, 0.f}, acc01 = {0.f, 0.f, 0.f, 0.f};
    f4 acc10 = {0.f, 0.f, 0.f, 0.f}, acc11 = {0.f, 0.f, 0.f, 0.f};
#pragma unroll
    for (int s = 0; s < 4; s++) {
      const int k = s * 32 + g * 8;
      const u16x8 a0 = *(const u16x8*)&sm[(wr1 * 32 + l15) * N_XS + k];
      const u16x8 a1 = *(const u16x8*)&sm[(wr1 * 32 + 16 + l15) * N_XS + k];
      acc00 = MF(a0, b1f[s][0], acc00);
      acc01 = MF(a0, b1f[s][1], acc01);
      acc10 = MF(a1, b1f[s][0], acc10);
      acc11 = MF(a1, b1f[s][1], acc11);
    }
#pragma unroll
    for (int reg = 0; reg < 4; reg++) {
      const int row0 = wr1 * 32 + 4 * g + reg;
      const int row1 = row0 + 16;
      sm[N_HO + row0 * N_XS + wc1 * 32 + l15] = f2h(fmaxf(acc00[reg] + bias1_0, 0.f));
      sm[N_HO + row0 * N_XS + wc1 * 32 + 16 + l15] = f2h(fmaxf(acc01[reg] + bias1_1, 0.f));
      sm[N_HO + row1 * N_XS + wc1 * 32 + l15] = f2h(fmaxf(acc10[reg] + bias1_0, 0.f));
      sm[N_HO + row1 * N_XS + wc1 * 32 + 16 + l15] = f2h(fmaxf(acc11[reg] + bias1_1, 0.f));
    }
    __syncthreads();

    // ---- layer 2 ----
    f4 a20 = {0.f, 0.f, 0.f, 0.f}, a21 = {0.f, 0.f, 0.f, 0.f};
#pragma unroll
    for (int s = 0; s < 4; s++) {
      const int k = s * 32 + g * 8;
      const u16x8 h0 = *(const u16x8*)&sm[N_HO + (wr2 * 32 + l15) * N_XS + k];
      const u16x8 h1 = *(const u16x8*)&sm[N_HO + (wr2 * 32 + 16 + l15) * N_XS + k];
      a20 = MF(h0, b2f[s], a20);
      a21 = MF(h1, b2f[s], a21);
    }
    {
      float* ob = (float*)&sm[N_OB];
#pragma unroll
      for (int reg = 0; reg < 4; reg++) {
        const int row0 = wr2 * 32 + 4 * g + reg;
        ob[row0 * 64 + wc2 * 16 + l15] = fmaxf(a20[reg] + bias2, 0.f);
        ob[(row0 + 16) * 64 + wc2 * 16 + l15] = fmaxf(a21[reg] + bias2, 0.f);
      }
    }
    __syncthreads();

    // ---- LayerNorm + store ----
    {
      const float* ob = (const float*)&sm[N_OB];
      const int p = t & 7;
      const f4 v0 = *(const f4*)&ob[r * 64 + p * 8];
      const f4 v1 = *(const f4*)&ob[r * 64 + p * 8 + 4];
      float s = 0.f, s2 = 0.f;
#pragma unroll
      for (int j = 0; j < 4; j++) {
        s += v0[j] + v1[j];
        s2 += v0[j] * v0[j] + v1[j] * v1[j];
      }
      s += __shfl_xor(s, 1);  s += __shfl_xor(s, 2);  s += __shfl_xor(s, 4);
      s2 += __shfl_xor(s2, 1); s2 += __shfl_xor(s2, 2); s2 += __shfl_xor(s2, 4);
      const float mu = s * (1.f / 64.f);
      const float var = s2 * (1.f / 64.f) - mu * mu;
      const float rstd = rsqrtf(var + 1e-5f);
      const long n = nbase + r;
      if (n < NN) {
        const f4 ga0 = *(const f4*)&gamma[p * 8];
        const f4 ga1 = *(const f4*)&gamma[p * 8 + 4];
        const f4 be0 = *(const f4*)&beta[p * 8];
        const f4 be1 = *(const f4*)&beta[p * 8 + 4];
        f4 o0, o1;
#pragma unroll
        for (int j = 0; j < 4; j++) {
          o0[j] = (v0[j] - mu) * rstd * ga0[j] + be0[j];
          o1[j] = (v1[j] - mu) * rstd * ga1[j] + be1[j];
        }
        float* op = node_out + (size_t)n * 64 + p * 8;
        __builtin_nontemporal_store(o0, (f4*)op);
        __builtin_nontemporal_store(o1, (f4*)(op + 4));
      }
    }
  }
}

extern "C" void kernel_launch(void* const* d_in, const int* in_sizes, int n_in,
                              void* d_out, int out_size, void* d_ws, size_t ws_size,
                              hipStream_t stream) {
  const float* edge_attr = (const float*)d_in[0];
  const float* node_attr = (const float*)d_in[1];
  const int* eidx = (const int*)d_in[2];
  // d_in[3] = batch (unused)
  const float* eW1 = (const float*)d_in[4];
  const float* eb1 = (const float*)d_in[5];
  const float* eW2 = (const float*)d_in[6];
  const float* eb2 = (const float*)d_in[7];
  const float* eg = (const float*)d_in[8];
  const float* ebt = (const float*)d_in[9];
  const float* nW1 = (const float*)d_in[10];
  const float* nb1 = (const float*)d_in[11];
  const float* nW2 = (const float*)d_in[12];
  const float* nb2 = (const float*)d_in[13];
  const float* ng = (const float*)d_in[14];
  const float* nbt = (const float*)d_in[15];

  float* out_edge = (float*)d_out;
  float* out_node = out_edge + (size_t)NE * 64;

  // workspace: nh (f16 node_attr, 6.4 MB) then CSR ints (round-13 layout)
  u16* nh = (u16*)d_ws;
  int* deg = (int*)((char*)d_ws + (size_t)NN * 64 * 2);
  int* offsets = deg + NN;
  int* cur = offsets + NN + 1;
  int* elist = cur + NN;

  const int n4 = NN * 64 / 4;
  cvt_kernel<<<(n4 + 255) / 256, 256, 0, stream>>>(node_attr, nh, deg, n4);
  hist_kernel<<<(NE + 255) / 256, 256, 0, stream>>>(eidx, deg);
  scan_kernel<<<1, 1024, 0, stream>>>(deg, offsets, cur);
  scatter_kernel<<<(NE + 255) / 256, 256, 0, stream>>>(eidx, cur, elist);

  const int etiles = NE / 64;         // 12500
  const int ntiles = (NN + 63) / 64;  // 782
  edge_mlp_kernel<<<512, 512, 0, stream>>>(edge_attr, nh, eidx,
                                           eW1, eb1, eW2, eb2, eg, ebt,
                                           out_edge, etiles);
  node_mlp_kernel<<<ntiles, 512, 0, stream>>>(nh, out_edge, offsets, elist,
                                              nW1, nb1, nW2, nb2, ng, nbt,
                                              out_node, ntiles);
}

// Round 18
// 312.466 us; speedup vs baseline: 2.0590x; 1.3477x over previous
//
#include <hip/hip_runtime.h>

typedef float f4 __attribute__((ext_vector_type(4)));
typedef _Float16 f16;
typedef f16 f16x8 __attribute__((ext_vector_type(8)));
typedef unsigned short u16;
typedef u16 u16x4 __attribute__((ext_vector_type(4)));
typedef u16 u16x8 __attribute__((ext_vector_type(8)));

#define NE 800000
#define NN 50000

static __device__ __forceinline__ f4 MF(u16x8 a, u16x8 b, f4 c) {
  return __builtin_amdgcn_mfma_f32_16x16x32_f16(
      __builtin_bit_cast(f16x8, a), __builtin_bit_cast(f16x8, b), c, 0, 0, 0);
}
static __device__ __forceinline__ u16 f2h(float x) {
  return __builtin_bit_cast(u16, (f16)x);
}

// ---------------- prologue kernels ----------------
__global__ void cvt_kernel(const float* __restrict__ na, u16* __restrict__ nh,
                           int* __restrict__ deg, int n4) {
  int i = blockIdx.x * blockDim.x + threadIdx.x;
  if (i < n4) {
    const f4 v = ((const f4*)na)[i];
    u16x4 h;
#pragma unroll
    for (int j = 0; j < 4; j++) h[j] = f2h(v[j]);
    ((u16x4*)nh)[i] = h;
  }
  if (i < NN) deg[i] = 0;
}

__global__ void hist_kernel(const int* __restrict__ eidx, int* __restrict__ deg) {
  int e = blockIdx.x * blockDim.x + threadIdx.x;
  if (e < NE) atomicAdd(&deg[eidx[NE + e]], 1);
}

// 64 blocks x 256 threads x 4 elems = 65536 slots >= NN
__global__ __launch_bounds__(256)
void scan_part_kernel(const int* __restrict__ deg, int* __restrict__ bsum) {
  __shared__ int red[256];
  const int t = threadIdx.x;
  const int base = (blockIdx.x * 256 + t) * 4;
  int s = 0;
#pragma unroll
  for (int j = 0; j < 4; j++) {
    const int i = base + j;
    if (i < NN) s += deg[i];
  }
  red[t] = s;
  __syncthreads();
  for (int d = 128; d > 0; d >>= 1) {
    if (t < d) red[t] += red[t + d];
    __syncthreads();
  }
  if (t == 0) bsum[blockIdx.x] = red[0];
}

__global__ void scan_top_kernel(const int* __restrict__ bsum,
                                int* __restrict__ boff) {
  if (threadIdx.x == 0) {
    int run = 0;
    for (int i = 0; i < 64; i++) {
      boff[i] = run;
      run += bsum[i];
    }
  }
}

__global__ __launch_bounds__(256)
void scan_fill_kernel(const int* __restrict__ deg, const int* __restrict__ boff,
                      int* __restrict__ offsets, int* __restrict__ cur) {
  __shared__ int buf[2][256];
  const int t = threadIdx.x;
  const int base = (blockIdx.x * 256 + t) * 4;
  int dj[4];
  int s = 0;
#pragma unroll
  for (int j = 0; j < 4; j++) {
    const int i = base + j;
    dj[j] = (i < NN) ? deg[i] : 0;
    s += dj[j];
  }
  buf[0][t] = s;
  __syncthreads();
  int src = 0;
  for (int d = 1; d < 256; d <<= 1) {
    int v = buf[src][t];
    if (t >= d) v += buf[src][t - d];
    buf[src ^ 1][t] = v;
    src ^= 1;
    __syncthreads();
  }
  int run = buf[src][t] - s + boff[blockIdx.x];  // exclusive prefix
#pragma unroll
  for (int j = 0; j < 4; j++) {
    const int i = base + j;
    if (i < NN) {
      offsets[i] = run;
      cur[i] = run;
      run += dj[j];
    }
  }
  if (blockIdx.x == 0 && t == 0) offsets[NN] = NE;
}

__global__ void scatter_kernel(const int* __restrict__ eidx, int* __restrict__ cur,
                               int* __restrict__ elist) {
  int e = blockIdx.x * blockDim.x + threadIdx.x;
  if (e < NE) {
    int slot = atomicAdd(&cur[eidx[NE + e]], 1);
    elist[slot] = e;
  }
}

// ---- aggregation: CSR gather at max occupancy (no LDS, no MFMA) ----
// one thread per (node, q-octet): 400000 threads
__global__ __launch_bounds__(256)
void agg_kernel(const float* __restrict__ edge_out,
                const int* __restrict__ offsets,
                const int* __restrict__ elist,
                float* __restrict__ agg) {
  const int gid = blockIdx.x * 256 + threadIdx.x;
  const int n = gid >> 3, q = gid & 7;
  if (n >= NN) return;
  float ac[8];
#pragma unroll
  for (int j = 0; j < 8; j++) ac[j] = 0.f;
  const int o0 = offsets[n], o1 = offsets[n + 1];
  int i = o0;
  for (; i + 8 <= o1; i += 8) {
    int e[8];
#pragma unroll
    for (int j = 0; j < 8; j++) e[j] = elist[i + j];
    f4 u0[8], u1[8];
#pragma unroll
    for (int j = 0; j < 8; j++) {
      u0[j] = *(const f4*)&edge_out[(size_t)e[j] * 64 + q * 8];
      u1[j] = *(const f4*)&edge_out[(size_t)e[j] * 64 + q * 8 + 4];
    }
#pragma unroll
    for (int j = 0; j < 8; j++)
#pragma unroll
      for (int k = 0; k < 4; k++) {
        ac[k] += u0[j][k];
        ac[k + 4] += u1[j][k];
      }
  }
  for (; i < o1; i++) {
    const int e = elist[i];
    const f4 u0 = *(const f4*)&edge_out[(size_t)e * 64 + q * 8];
    const f4 u1 = *(const f4*)&edge_out[(size_t)e * 64 + q * 8 + 4];
#pragma unroll
    for (int j = 0; j < 4; j++) {
      ac[j] += u0[j];
      ac[j + 4] += u1[j];
    }
  }
  f4 o0v, o1v;
#pragma unroll
  for (int j = 0; j < 4; j++) {
    o0v[j] = ac[j];
    o1v[j] = ac[j + 4];
  }
  float* ap = agg + (size_t)n * 64 + q * 8;
  *(f4*)ap = o0v;
  *(f4*)(ap + 4) = o1v;
}

// ---- edge kernel LDS (u16 units): 64-row tiles (round-17 proven, exact) ----
#define E_XS 200
#define E_HS 136
#define E_HO 12800
#define E_OB 21504

__global__ __launch_bounds__(512, 4)
void edge_mlp_kernel(const float* __restrict__ edge_attr,
                     const u16* __restrict__ nh,
                     const int* __restrict__ eidx,
                     const float* __restrict__ W1, const float* __restrict__ b1,
                     const float* __restrict__ W2, const float* __restrict__ b2,
                     const float* __restrict__ gamma, const float* __restrict__ beta,
                     float* __restrict__ edge_out, int ntiles) {
  __shared__ __align__(16) u16 sm[29696];
  const int t = threadIdx.x;
  const int wid = t >> 6, lane = t & 63, g = lane >> 4, l15 = lane & 15;
  const int wr1 = wid >> 2, wc1 = wid & 3;  // L1: 32 rows x 32 cols per wave
  const int wr2 = wid & 1, wc2 = wid >> 1;  // L2: 32 rows x 16 cols per wave

  u16x8 b1f[6][2], b2f[4];
#pragma unroll
  for (int s = 0; s < 6; s++)
#pragma unroll
    for (int ci = 0; ci < 2; ci++) {
      const int col = wc1 * 32 + ci * 16 + l15;
      u16x8 th;
#pragma unroll
      for (int i = 0; i < 8; i++) th[i] = f2h(W1[(s * 32 + g * 8 + i) * 128 + col]);
      b1f[s][ci] = th;
    }
#pragma unroll
  for (int s = 0; s < 4; s++) {
    const int col = wc2 * 16 + l15;
    u16x8 th;
#pragma unroll
    for (int i = 0; i < 8; i++) th[i] = f2h(W2[(s * 32 + g * 8 + i) * 64 + col]);
    b2f[s] = th;
  }
  const float bias1_0 = b1[wc1 * 32 + l15];
  const float bias1_1 = b1[wc1 * 32 + 16 + l15];
  const float bias2 = b2[wc2 * 16 + l15];

  const int r = t >> 3;
  const int c8 = (t & 7) * 8;

  int idxr, idxs;
  u16x8 grecv, gsend;
  f4 ge0, ge1;

#define IDX(TB)                                                \
  {                                                            \
    const long e_ = (long)(TB)*64 + r;                         \
    idxr = eidx[NE + e_];                                      \
    idxs = eidx[e_];                                           \
  }
#define ROWS(TB)                                               \
  {                                                            \
    grecv = *(const u16x8*)&nh[(size_t)idxr * 64 + c8];        \
    gsend = *(const u16x8*)&nh[(size_t)idxs * 64 + c8];        \
    const float* ep_ =                                         \
        &edge_attr[((size_t)(TB)*64 + r) * 64 + c8];           \
    ge0 = __builtin_nontemporal_load((const f4*)ep_);          \
    ge1 = __builtin_nontemporal_load((const f4*)(ep_ + 4));    \
  }

  const int G = gridDim.x;
  const int last = ntiles - 1;
  IDX(blockIdx.x);
  ROWS(blockIdx.x);
  {
    int tn = blockIdx.x + G;
    if (tn > last) tn = last;
    IDX(tn);
  }

  for (int tile = blockIdx.x; tile < ntiles; tile += G) {
    // ---- write prefetched x tile -> LDS ----
    *(u16x8*)&sm[r * E_XS + c8] = grecv;
    *(u16x8*)&sm[r * E_XS + 64 + c8] = gsend;
    {
      u16x8 he;
#pragma unroll
      for (int j = 0; j < 4; j++) {
        he[j] = f2h(ge0[j]);
        he[4 + j] = f2h(ge1[j]);
      }
      *(u16x8*)&sm[r * E_XS + 128 + c8] = he;
    }
    __syncthreads();  // B1: x visible

    // ---- issue next tile's rows (indices ready) + indices two ahead ----
    {
      int tn = tile + G;
      if (tn > last) tn = last;
      ROWS(tn);
      int tn2 = tile + 2 * G;
      if (tn2 > last) tn2 = last;
      IDX(tn2);
    }

    // ---- layer 1: per-wave 32x32 tile of h = relu(x @ W1 + b1) ----
    f4 acc00 = {0.f, 0.f, 0.f, 0.f}, acc01 = {0.f, 0.f, 0.f, 0.f};
    f4 acc10 = {0.f, 0.f, 0.f, 0.f}, acc11 = {0.f, 0.f, 0.f, 0.f};
#pragma unroll
    for (int s = 0; s < 6; s++) {
      const int k = s * 32 + g * 8;
      const u16x8 a0 = *(const u16x8*)&sm[(wr1 * 32 + l15) * E_XS + k];
      const u16x8 a1 = *(const u16x8*)&sm[(wr1 * 32 + 16 + l15) * E_XS + k];
      acc00 = MF(a0, b1f[s][0], acc00);
      acc01 = MF(a0, b1f[s][1], acc01);
      acc10 = MF(a1, b1f[s][0], acc10);
      acc11 = MF(a1, b1f[s][1], acc11);
    }
#pragma unroll
    for (int reg = 0; reg < 4; reg++) {
      const int row0 = wr1 * 32 + 4 * g + reg;
      const int row1 = row0 + 16;
      sm[E_HO + row0 * E_HS + wc1 * 32 + l15] = f2h(fmaxf(acc00[reg] + bias1_0, 0.f));
      sm[E_HO + row0 * E_HS + wc1 * 32 + 16 + l15] = f2h(fmaxf(acc01[reg] + bias1_1, 0.f));
      sm[E_HO + row1 * E_HS + wc1 * 32 + l15] = f2h(fmaxf(acc10[reg] + bias1_0, 0.f));
      sm[E_HO + row1 * E_HS + wc1 * 32 + 16 + l15] = f2h(fmaxf(acc11[reg] + bias1_1, 0.f));
    }
    __syncthreads();  // B2: h visible

    // ---- layer 2: per-wave 32x16 tile of o = relu(h @ W2 + b2) ----
    f4 a20 = {0.f, 0.f, 0.f, 0.f}, a21 = {0.f, 0.f, 0.f, 0.f};
#pragma unroll
    for (int s = 0; s < 4; s++) {
      const int k = s * 32 + g * 8;
      const u16x8 h0 = *(const u16x8*)&sm[E_HO + (wr2 * 32 + l15) * E_HS + k];
      const u16x8 h1 = *(const u16x8*)&sm[E_HO + (wr2 * 32 + 16 + l15) * E_HS + k];
      a20 = MF(h0, b2f[s], a20);
      a21 = MF(h1, b2f[s], a21);
    }
    {
      float* ob = (float*)&sm[E_OB];
#pragma unroll
      for (int reg = 0; reg < 4; reg++) {
        const int row0 = wr2 * 32 + 4 * g + reg;
        ob[row0 * 64 + wc2 * 16 + l15] = fmaxf(a20[reg] + bias2, 0.f);
        ob[(row0 + 16) * 64 + wc2 * 16 + l15] = fmaxf(a21[reg] + bias2, 0.f);
      }
    }
    __syncthreads();  // B3: ob visible (also fences x reads before next x write)

    // ---- LayerNorm + store (all 512 threads: 64 rows x 8 lanes) ----
    {
      const float* ob = (const float*)&sm[E_OB];
      const int p = t & 7;
      const f4 v0 = *(const f4*)&ob[r * 64 + p * 8];
      const f4 v1 = *(const f4*)&ob[r * 64 + p * 8 + 4];
      float s = 0.f, s2 = 0.f;
#pragma unroll
      for (int j = 0; j < 4; j++) {
        s += v0[j] + v1[j];
        s2 += v0[j] * v0[j] + v1[j] * v1[j];
      }
      s += __shfl_xor(s, 1);  s += __shfl_xor(s, 2);  s += __shfl_xor(s, 4);
      s2 += __shfl_xor(s2, 1); s2 += __shfl_xor(s2, 2); s2 += __shfl_xor(s2, 4);
      const float mu = s * (1.f / 64.f);
      const float var = s2 * (1.f / 64.f) - mu * mu;
      const float rstd = rsqrtf(var + 1e-5f);
      const f4 ga0 = *(const f4*)&gamma[p * 8];
      const f4 ga1 = *(const f4*)&gamma[p * 8 + 4];
      const f4 be0 = *(const f4*)&beta[p * 8];
      const f4 be1 = *(const f4*)&beta[p * 8 + 4];
      f4 o0, o1;
#pragma unroll
      for (int j = 0; j < 4; j++) {
        o0[j] = (v0[j] - mu) * rstd * ga0[j] + be0[j];
        o1[j] = (v1[j] - mu) * rstd * ga1[j] + be1[j];
      }
      float* op = edge_out + ((size_t)tile * 64 + r) * 64 + p * 8;
      *(f4*)op = o0;
      *(f4*)(op + 4) = o1;
    }
  }
#undef IDX
#undef ROWS
}

// ---- node kernel LDS (u16): 64-row tiles; linear agg read ----
#define N_XS 136
#define N_HO 8704
#define N_OB 17408

__global__ __launch_bounds__(512, 4)
void node_mlp_kernel(const u16* __restrict__ nh,
                     const float* __restrict__ agg,
                     const float* __restrict__ W1, const float* __restrict__ b1,
                     const float* __restrict__ W2, const float* __restrict__ b2,
                     const float* __restrict__ gamma, const float* __restrict__ beta,
                     float* __restrict__ node_out, int ntiles) {
  __shared__ __align__(16) u16 sm[25600];
  const int t = threadIdx.x;
  const int wid = t >> 6, lane = t & 63, g = lane >> 4, l15 = lane & 15;
  const int wr1 = wid >> 2, wc1 = wid & 3;
  const int wr2 = wid & 1, wc2 = wid >> 1;

  u16x8 b1f[4][2], b2f[4];
#pragma unroll
  for (int s = 0; s < 4; s++)
#pragma unroll
    for (int ci = 0; ci < 2; ci++) {
      const int col = wc1 * 32 + ci * 16 + l15;
      u16x8 th;
#pragma unroll
      for (int i = 0; i < 8; i++) th[i] = f2h(W1[(s * 32 + g * 8 + i) * 128 + col]);
      b1f[s][ci] = th;
    }
#pragma unroll
  for (int s = 0; s < 4; s++) {
    const int col = wc2 * 16 + l15;
    u16x8 th;
#pragma unroll
    for (int i = 0; i < 8; i++) th[i] = f2h(W2[(s * 32 + g * 8 + i) * 64 + col]);
    b2f[s] = th;
  }
  const float bias1_0 = b1[wc1 * 32 + l15];
  const float bias1_1 = b1[wc1 * 32 + 16 + l15];
  const float bias2 = b2[wc2 * 16 + l15];

  const int r = t >> 3, q = t & 7;

  for (int tile = blockIdx.x; tile < ntiles; tile += gridDim.x) {
    const long nbase = (long)tile * 64;
    __syncthreads();  // protect LDS across iterations

    // ---- stage x = [node_attr(f16) | agg(f32, linear)] ----
    {
      const long n = nbase + r;
      u16x8 ha = {0, 0, 0, 0, 0, 0, 0, 0};
      u16x8 hb = {0, 0, 0, 0, 0, 0, 0, 0};
      if (n < NN) {
        ha = *(const u16x8*)&nh[(size_t)n * 64 + q * 8];
        const f4 a0 = *(const f4*)&agg[(size_t)n * 64 + q * 8];
        const f4 a1 = *(const f4*)&agg[(size_t)n * 64 + q * 8 + 4];
#pragma unroll
        for (int j = 0; j < 4; j++) {
          hb[j] = f2h(a0[j]);
          hb[4 + j] = f2h(a1[j]);
        }
      }
      *(u16x8*)&sm[r * N_XS + q * 8] = ha;
      *(u16x8*)&sm[r * N_XS + 64 + q * 8] = hb;
    }
    __syncthreads();

    // ---- layer 1 ----
    f4 acc00 = {0.f, 0.f, 0.f, 0.f}, acc01 = {0.f, 0.f, 0.f, 0.f};
    f4 acc10 = {0.f, 0.f, 0.f, 0.f}, acc11 = {0.f, 0.f, 0.f, 0.f};
#pragma unroll
    for (int s = 0; s < 4; s++) {
      const int k = s * 32 + g * 8;
      const u16x8 a0 = *(const u16x8*)&sm[(wr1 * 32 + l15) * N_XS + k];
      const u16x8 a1 = *(const u16x8*)&sm[(wr1 * 32 + 16 + l15) * N_XS + k];
      acc00 = MF(a0, b1f[s][0], acc00);
      acc01 = MF(a0, b1f[s][1], acc01);
      acc10 = MF(a1, b1f[s][0], acc10);
      acc11 = MF(a1, b1f[s][1], acc11);
    }
#pragma unroll
    for (int reg = 0; reg < 4; reg++) {
      const int row0 = wr1 * 32 + 4 * g + reg;
      const int row1 = row0 + 16;
      sm[N_HO + row0 * N_XS + wc1 * 32 + l15] = f2h(fmaxf(acc00[reg] + bias1_0, 0.f));
      sm[N_HO + row0 * N_XS + wc1 * 32 + 16 + l15] = f2h(fmaxf(acc01[reg] + bias1_1, 0.f));
      sm[N_HO + row1 * N_XS + wc1 * 32 + l15] = f2h(fmaxf(acc10[reg] + bias1_0, 0.f));
      sm[N_HO + row1 * N_XS + wc1 * 32 + 16 + l15] = f2h(fmaxf(acc11[reg] + bias1_1, 0.f));
    }
    __syncthreads();

    // ---- layer 2 ----
    f4 a20 = {0.f, 0.f, 0.f, 0.f}, a21 = {0.f, 0.f, 0.f, 0.f};
#pragma unroll
    for (int s = 0; s < 4; s++) {
      const int k = s * 32 + g * 8;
      const u16x8 h0 = *(const u16x8*)&sm[N_HO + (wr2 * 32 + l15) * N_XS + k];
      const u16x8 h1 = *(const u16x8*)&sm[N_HO + (wr2 * 32 + 16 + l15) * N_XS + k];
      a20 = MF(h0, b2f[s], a20);
      a21 = MF(h1, b2f[s], a21);
    }
    {
      float* ob = (float*)&sm[N_OB];
#pragma unroll
      for (int reg = 0; reg < 4; reg++) {
        const int row0 = wr2 * 32 + 4 * g + reg;
        ob[row0 * 64 + wc2 * 16 + l15] = fmaxf(a20[reg] + bias2, 0.f);
        ob[(row0 + 16) * 64 + wc2 * 16 + l15] = fmaxf(a21[reg] + bias2, 0.f);
      }
    }
    __syncthreads();

    // ---- LayerNorm + store ----
    {
      const float* ob = (const float*)&sm[N_OB];
      const int p = t & 7;
      const f4 v0 = *(const f4*)&ob[r * 64 + p * 8];
      const f4 v1 = *(const f4*)&ob[r * 64 + p * 8 + 4];
      float s = 0.f, s2 = 0.f;
#pragma unroll
      for (int j = 0; j < 4; j++) {
        s += v0[j] + v1[j];
        s2 += v0[j] * v0[j] + v1[j] * v1[j];
      }
      s += __shfl_xor(s, 1);  s += __shfl_xor(s, 2);  s += __shfl_xor(s, 4);
      s2 += __shfl_xor(s2, 1); s2 += __shfl_xor(s2, 2); s2 += __shfl_xor(s2, 4);
      const float mu = s * (1.f / 64.f);
      const float var = s2 * (1.f / 64.f) - mu * mu;
      const float rstd = rsqrtf(var + 1e-5f);
      const long n = nbase + r;
      if (n < NN) {
        const f4 ga0 = *(const f4*)&gamma[p * 8];
        const f4 ga1 = *(const f4*)&gamma[p * 8 + 4];
        const f4 be0 = *(const f4*)&beta[p * 8];
        const f4 be1 = *(const f4*)&beta[p * 8 + 4];
        f4 o0, o1;
#pragma unroll
        for (int j = 0; j < 4; j++) {
          o0[j] = (v0[j] - mu) * rstd * ga0[j] + be0[j];
          o1[j] = (v1[j] - mu) * rstd * ga1[j] + be1[j];
        }
        float* op = node_out + (size_t)n * 64 + p * 8;
        __builtin_nontemporal_store(o0, (f4*)op);
        __builtin_nontemporal_store(o1, (f4*)(op + 4));
      }
    }
  }
}

extern "C" void kernel_launch(void* const* d_in, const int* in_sizes, int n_in,
                              void* d_out, int out_size, void* d_ws, size_t ws_size,
                              hipStream_t stream) {
  const float* edge_attr = (const float*)d_in[0];
  const float* node_attr = (const float*)d_in[1];
  const int* eidx = (const int*)d_in[2];
  // d_in[3] = batch (unused)
  const float* eW1 = (const float*)d_in[4];
  const float* eb1 = (const float*)d_in[5];
  const float* eW2 = (const float*)d_in[6];
  const float* eb2 = (const float*)d_in[7];
  const float* eg = (const float*)d_in[8];
  const float* ebt = (const float*)d_in[9];
  const float* nW1 = (const float*)d_in[10];
  const float* nb1 = (const float*)d_in[11];
  const float* nW2 = (const float*)d_in[12];
  const float* nb2 = (const float*)d_in[13];
  const float* ng = (const float*)d_in[14];
  const float* nbt = (const float*)d_in[15];

  float* out_edge = (float*)d_out;
  float* out_node = out_edge + (size_t)NE * 64;

  // workspace: nh (6.4 MB) | ints (incl. bsum/boff) | agg (12.8 MB f32)
  u16* nh = (u16*)d_ws;
  int* deg = (int*)((char*)d_ws + (size_t)NN * 64 * 2);
  int* offsets = deg + NN;
  int* cur = offsets + NN + 1;
  int* bsum = cur + NN;
  int* boff = bsum + 64;
  int* elist = boff + 64;
  float* agg = (float*)(elist + NE);

  const int n4 = NN * 64 / 4;
  cvt_kernel<<<(n4 + 255) / 256, 256, 0, stream>>>(node_attr, nh, deg, n4);
  hist_kernel<<<(NE + 255) / 256, 256, 0, stream>>>(eidx, deg);
  scan_part_kernel<<<64, 256, 0, stream>>>(deg, bsum);
  scan_top_kernel<<<1, 64, 0, stream>>>(bsum, boff);
  scan_fill_kernel<<<64, 256, 0, stream>>>(deg, boff, offsets, cur);
  scatter_kernel<<<(NE + 255) / 256, 256, 0, stream>>>(eidx, cur, elist);

  const int etiles = NE / 64;         // 12500
  const int ntiles = (NN + 63) / 64;  // 782
  edge_mlp_kernel<<<512, 512, 0, stream>>>(edge_attr, nh, eidx,
                                           eW1, eb1, eW2, eb2, eg, ebt,
                                           out_edge, etiles);
  agg_kernel<<<(NN * 8 + 255) / 256, 256, 0, stream>>>(out_edge, offsets, elist,
                                                       agg);
  node_mlp_kernel<<<ntiles, 512, 0, stream>>>(nh, agg,
                                              nW1, nb1, nW2, nb2, ng, nbt,
                                              out_node, ntiles);
}